// Round 7
// baseline (279.089 us; speedup 1.0000x reference)
//
#include <hip/hip_runtime.h>

// SAGEConv x2 forward. CSR via bucketed two-pass binning. gemm1 + gemm2 on
// MFMA (bf16 in, fp32 acc). Aggregation: pure-gather kernels, sub-wave
// groups, bf16 uint4 payloads, 16 gathers in flight per wave.

constexpr int IN_DIM  = 128;
constexpr int HID     = 64;
constexpr int OUT_DIM = 32;
constexpr float SLOPE = 0.1f;
constexpr int NPB_SHIFT = 8;     // 256 nodes per bucket
constexpr int NBMAX = 512;       // max buckets (N <= 131072)
constexpr int CHUNK = 4096;      // edges per partition block

typedef unsigned int uint32;
typedef unsigned short ushort16;

__device__ inline float blo(uint32 u) { return __uint_as_float(u << 16); }
__device__ inline float bhi(uint32 u) { return __uint_as_float(u & 0xffff0000u); }
__device__ inline ushort16 f2b(float f) {
    uint32 u = __float_as_uint(f);
    u += 0x7fffu + ((u >> 16) & 1u);   // round-to-nearest-even
    return (ushort16)(u >> 16);
}
__device__ inline uint32 pack2(float lo, float hi) {
    return (uint32)f2b(lo) | ((uint32)f2b(hi) << 16);
}
__device__ inline void addup(float* acc, uint4 u) {
    acc[0] += blo(u.x); acc[1] += bhi(u.x);
    acc[2] += blo(u.y); acc[3] += bhi(u.y);
    acc[4] += blo(u.z); acc[5] += bhi(u.z);
    acc[6] += blo(u.w); acc[7] += bhi(u.w);
}

__global__ __launch_bounds__(256) void bucket_hist_kernel(
    const int* __restrict__ dst, int* __restrict__ bhist, int E) {
    __shared__ int bh[NBMAX];
    for (int i = threadIdx.x; i < NBMAX; i += 256) bh[i] = 0;
    __syncthreads();
    for (int e = blockIdx.x * 256 + threadIdx.x; e < E; e += gridDim.x * 256)
        atomicAdd(&bh[dst[e] >> NPB_SHIFT], 1);
    __syncthreads();
    for (int b = threadIdx.x; b < NBMAX; b += 256)
        if (bh[b]) atomicAdd(&bhist[b], bh[b]);
}

__global__ __launch_bounds__(512) void bucket_scan_kernel(
    const int* __restrict__ bhist, int* __restrict__ ebase,
    int* __restrict__ pbase, int* __restrict__ bcur,
    int* __restrict__ rowptr, int NB, int N, int E) {
    __shared__ int s1[512], s2[512];
    const int t = threadIdx.x;
    int bh = (t < NB) ? bhist[t] : 0;
    int pd = (bh + 15) & ~15;
    s1[t] = bh; s2[t] = pd; __syncthreads();
    for (int off = 1; off < 512; off <<= 1) {
        int a = (t >= off) ? s1[t - off] : 0;
        int b = (t >= off) ? s2[t - off] : 0;
        __syncthreads();
        s1[t] += a; s2[t] += b;
        __syncthreads();
    }
    ebase[t] = s1[t] - bh;
    pbase[t] = s2[t] - pd;
    bcur[t]  = s2[t] - pd;
    if (t == 0) rowptr[N] = E;
}

__global__ __launch_bounds__(256) void partition_kernel(
    const int* __restrict__ src, const int* __restrict__ dst,
    int* __restrict__ bcur, uint32* __restrict__ pairs, int E, int NB) {
    __shared__ int hist[NBMAX], loff[NBMAX], cur[NBMAX];
    __shared__ int s[256];
    __shared__ uint32 stage[CHUNK];
    const int tid = threadIdx.x;
    const int e0  = blockIdx.x * CHUNK;
    const int cnt = min(CHUNK, E - e0);
    for (int i = tid; i < NBMAX; i += 256) hist[i] = 0;
    __syncthreads();
    int sreg[16], dreg[16];
#pragma unroll
    for (int k = 0; k < 16; ++k) {
        int i = tid + k * 256;
        if (i < cnt) {
            sreg[k] = src[e0 + i];
            dreg[k] = dst[e0 + i];
            atomicAdd(&hist[dreg[k] >> NPB_SHIFT], 1);
        }
    }
    __syncthreads();
    int a0 = hist[2 * tid], a1 = hist[2 * tid + 1];
    s[tid] = a0 + a1; __syncthreads();
    for (int off = 1; off < 256; off <<= 1) {
        int t = (tid >= off) ? s[tid - off] : 0;
        __syncthreads();
        s[tid] += t;
        __syncthreads();
    }
    int ex = s[tid] - (a0 + a1);
    loff[2 * tid] = ex;      loff[2 * tid + 1] = ex + a0;
    cur[2 * tid]  = ex;      cur[2 * tid + 1]  = ex + a0;
    __syncthreads();
#pragma unroll
    for (int k = 0; k < 16; ++k) {
        int i = tid + k * 256;
        if (i < cnt) {
            int b = dreg[k] >> NPB_SHIFT;
            int pos = atomicAdd(&cur[b], 1);
            stage[pos] = (uint32)sreg[k] | ((uint32)(dreg[k] & 255) << 24);
        }
    }
    __syncthreads();
    for (int b = tid; b < NB; b += 256) {
        int cb = hist[b];
        if (cb) {
            int g  = atomicAdd(&bcur[b], cb);
            int lb = loff[b];
            for (int k = 0; k < cb; ++k) pairs[g + k] = stage[lb + k];
        }
    }
}

__global__ __launch_bounds__(256) void fine_bin_kernel(
    const uint32* __restrict__ pairs, const int* __restrict__ bhist,
    const int* __restrict__ ebase, const int* __restrict__ pbase,
    int* __restrict__ rowptr, int* __restrict__ srcs, int N) {
    __shared__ int h2[256], cur[256], s[256];
    const int tid  = threadIdx.x;
    const int b    = blockIdx.x;
    const int n0   = b << NPB_SHIFT;
    const int base = pbase[b];
    const int sz   = bhist[b];
    h2[tid] = 0;
    __syncthreads();
    for (int i = tid; i < sz; i += 256)
        atomicAdd(&h2[pairs[base + i] >> 24], 1);
    __syncthreads();
    int v = h2[tid]; s[tid] = v; __syncthreads();
    for (int off = 1; off < 256; off <<= 1) {
        int t = (tid >= off) ? s[tid - off] : 0;
        __syncthreads();
        s[tid] += t;
        __syncthreads();
    }
    int rp = ebase[b] + s[tid] - v;
    int n  = n0 + tid;
    if (n < N) rowptr[n] = rp;
    cur[tid] = rp;
    __syncthreads();
    for (int i = tid; i < sz; i += 256) {
        uint32 u = pairs[base + i];
        int p = atomicAdd(&cur[u >> 24], 1);
        srcs[p] = (int)(u & 0xFFFFFFu);
    }
}

// ---- MFMA gemm1: x[N,128] @ [Wl1|Wr1] -> xl bf16[N,64], xr fp32[N,64]+b1 ----
__global__ __launch_bounds__(256) void gemm1_mfma_kernel(
    const float* __restrict__ x, const float* __restrict__ Wl,
    const float* __restrict__ Wr, const float* __restrict__ b1,
    ushort16* __restrict__ xl, float* __restrict__ xr, int N) {
    using frag = __attribute__((ext_vector_type(8))) short;
    using f32x4 = __attribute__((ext_vector_type(4))) float;
    constexpr int LDA = IN_DIM + 8;
    __shared__ ushort16 Ash[64][LDA];
    __shared__ ushort16 Bsh[128][LDA];
    const int tid = threadIdx.x;
    const int n0  = blockIdx.x * 64;
    {
        const int c = tid & 63;
        for (int k = tid >> 6; k < IN_DIM; k += 4) {
            Bsh[c][k]      = f2b(Wl[k * HID + c]);
            Bsh[c + 64][k] = f2b(Wr[k * HID + c]);
        }
    }
    {
        const int lc  = (tid & 31) * 4;
        for (int row = tid >> 5; row < 64; row += 8) {
            int node = n0 + row;
            float4 xv = (node < N)
                ? *reinterpret_cast<const float4*>(&x[(long)node * IN_DIM + lc])
                : float4{0.f, 0.f, 0.f, 0.f};
            ushort16 pk[4] = {f2b(xv.x), f2b(xv.y), f2b(xv.z), f2b(xv.w)};
            *reinterpret_cast<ushort2*>(&Ash[row][lc])     = ushort2{pk[0], pk[1]};
            *reinterpret_cast<ushort2*>(&Ash[row][lc + 2]) = ushort2{pk[2], pk[3]};
        }
    }
    __syncthreads();
    const int lane = tid & 63;
    const int m0   = (tid >> 6) * 16;
    const int mlo  = lane & 15;
    const int qk   = lane >> 4;
    frag Af[4];
#pragma unroll
    for (int kc = 0; kc < 4; ++kc)
        Af[kc] = *reinterpret_cast<const frag*>(&Ash[m0 + mlo][kc * 32 + qk * 8]);
#pragma unroll
    for (int ct = 0; ct < 8; ++ct) {
        f32x4 acc = {0.f, 0.f, 0.f, 0.f};
#pragma unroll
        for (int kc = 0; kc < 4; ++kc) {
            frag Bf = *reinterpret_cast<const frag*>(&Bsh[ct * 16 + mlo][kc * 32 + qk * 8]);
            acc = __builtin_amdgcn_mfma_f32_16x16x32_bf16(Af[kc], Bf, acc, 0, 0, 0);
        }
        const int col = ct * 16 + mlo;
#pragma unroll
        for (int r = 0; r < 4; ++r) {
            int node = n0 + m0 + qk * 4 + r;
            if (node < N) {
                if (col < HID) xl[(long)node * HID + col] = f2b(acc[r]);
                else           xr[(long)node * HID + (col - HID)] = acc[r] + b1[col - HID];
            }
        }
    }
}

// ---- agg1: h = LR(gather-sum(xl)*dinv + xr), h bf16[N,64] ----
// 8 lanes per node, 8 nodes per wave, 16 gathers in flight.
__global__ __launch_bounds__(256) void agg1_kernel(
    const int* __restrict__ rowptr, const int* __restrict__ srcs,
    const uint4* __restrict__ xlq,   // row n at xlq + n*8
    const float* __restrict__ xr,
    uint4* __restrict__ hq, int N) { // row n at hq + n*8
    const int lane  = threadIdx.x & 63;
    const int li    = lane & 7;
    const int gbase = lane & 56;
    const int wave  = (blockIdx.x << 2) + (threadIdx.x >> 6);
    const int n     = wave * 8 + (lane >> 3);
    if (n >= N) return;
    const int rp = rowptr[n];
    const int d  = rowptr[n + 1] - rp;
    float acc[8] = {};
    int j = 0;
    while (j + 16 <= d) {
        int sA = srcs[rp + j + li];
        int sB = srcs[rp + j + 8 + li];
        uint4 u0[8], u1[8];
#pragma unroll
        for (int t = 0; t < 8; ++t) {
            int s = __shfl(sA, gbase + t);
            u0[t] = xlq[(long)s * 8 + li];
        }
#pragma unroll
        for (int t = 0; t < 8; ++t) {
            int s = __shfl(sB, gbase + t);
            u1[t] = xlq[(long)s * 8 + li];
        }
#pragma unroll
        for (int t = 0; t < 8; ++t) { addup(acc, u0[t]); addup(acc, u1[t]); }
        j += 16;
    }
    if (j + 8 <= d) {
        int sA = srcs[rp + j + li];
        uint4 u0[8];
#pragma unroll
        for (int t = 0; t < 8; ++t) {
            int s = __shfl(sA, gbase + t);
            u0[t] = xlq[(long)s * 8 + li];
        }
#pragma unroll
        for (int t = 0; t < 8; ++t) addup(acc, u0[t]);
        j += 8;
    }
    int r = d - j;                     // 0..7
    if (r > 0) {
        int sA = srcs[rp + j + ((li < r) ? li : 0)];
#pragma unroll
        for (int t = 0; t < 7; ++t) {
            if (t < r) {
                int s = __shfl(sA, gbase + t);
                uint4 u = xlq[(long)s * 8 + li];
                addup(acc, u);
            }
        }
    }
    const float dinv = (d > 0) ? (1.f / (float)d) : 1.f;
    float4 xrA = *reinterpret_cast<const float4*>(&xr[(long)n * HID + 8 * li]);
    float4 xrB = *reinterpret_cast<const float4*>(&xr[(long)n * HID + 8 * li + 4]);
    float h[8];
    h[0] = fmaf(acc[0], dinv, xrA.x); h[1] = fmaf(acc[1], dinv, xrA.y);
    h[2] = fmaf(acc[2], dinv, xrA.z); h[3] = fmaf(acc[3], dinv, xrA.w);
    h[4] = fmaf(acc[4], dinv, xrB.x); h[5] = fmaf(acc[5], dinv, xrB.y);
    h[6] = fmaf(acc[6], dinv, xrB.z); h[7] = fmaf(acc[7], dinv, xrB.w);
#pragma unroll
    for (int t = 0; t < 8; ++t) h[t] = (h[t] > 0.f) ? h[t] : SLOPE * h[t];
    uint4 pk;
    pk.x = pack2(h[0], h[1]); pk.y = pack2(h[2], h[3]);
    pk.z = pack2(h[4], h[5]); pk.w = pack2(h[6], h[7]);
    hq[(long)n * 8 + li] = pk;
}

// ---- MFMA gemm2: h bf16[N,64] @ [Wl2|Wr2] -> hl bf16[N,32], hr fp32[N,32]+b2
// A-frags straight from global (16 rows x 16B per wave, coalesced); B in LDS.
__global__ __launch_bounds__(256) void gemm2_mfma_kernel(
    const ushort16* __restrict__ hs, const float* __restrict__ Wl2,
    const float* __restrict__ Wr2, const float* __restrict__ b2,
    ushort16* __restrict__ hl, float* __restrict__ hr, int N) {
    using frag = __attribute__((ext_vector_type(8))) short;
    using f32x4 = __attribute__((ext_vector_type(4))) float;
    __shared__ ushort16 Bsh[64][72];   // [col][k], cols 0..31=Wl2, 32..63=Wr2
    const int tid = threadIdx.x;
    const int n0  = blockIdx.x * 64;
    {
        const int c = tid & 63;
        for (int k = tid >> 6; k < HID; k += 4) {
            float w = (c < OUT_DIM) ? Wl2[k * OUT_DIM + c]
                                    : Wr2[k * OUT_DIM + (c - OUT_DIM)];
            Bsh[c][k] = f2b(w);
        }
    }
    __syncthreads();
    const int lane = tid & 63;
    const int m0   = (tid >> 6) * 16;
    const int mlo  = lane & 15;
    const int qk   = lane >> 4;
    const int row  = n0 + m0 + mlo;
    const int arow = (row < N) ? row : 0;     // clamp: garbage rows discarded
    frag Af[2];
#pragma unroll
    for (int kc = 0; kc < 2; ++kc)
        Af[kc] = *reinterpret_cast<const frag*>(&hs[(long)arow * HID + kc * 32 + qk * 8]);
#pragma unroll
    for (int ct = 0; ct < 4; ++ct) {
        f32x4 acc = {0.f, 0.f, 0.f, 0.f};
#pragma unroll
        for (int kc = 0; kc < 2; ++kc) {
            frag Bf = *reinterpret_cast<const frag*>(&Bsh[ct * 16 + mlo][kc * 32 + qk * 8]);
            acc = __builtin_amdgcn_mfma_f32_16x16x32_bf16(Af[kc], Bf, acc, 0, 0, 0);
        }
        const int col = ct * 16 + mlo;        // 0..63
#pragma unroll
        for (int r = 0; r < 4; ++r) {
            int node = n0 + m0 + qk * 4 + r;
            if (node < N) {
                if (col < OUT_DIM) hl[(long)node * OUT_DIM + col] = f2b(acc[r]);
                else hr[(long)node * OUT_DIM + (col - OUT_DIM)] = acc[r] + b2[col - OUT_DIM];
            }
        }
    }
}

// ---- agg2: z = LR(gather-sum(hl)*dinv + hr) ----
// 4 lanes per node, 16 nodes per wave, 16 gathers in flight.
__global__ __launch_bounds__(256) void agg2_final_kernel(
    const int* __restrict__ rowptr, const int* __restrict__ srcs,
    const uint4* __restrict__ hlq,   // row n at hlq + n*4
    const float* __restrict__ hr,
    float* __restrict__ z, int N) {
    const int lane  = threadIdx.x & 63;
    const int li    = lane & 3;
    const int gbase = lane & 60;
    const int wave  = (blockIdx.x << 2) + (threadIdx.x >> 6);
    const int n     = wave * 16 + (lane >> 2);
    if (n >= N) return;
    const int rp = rowptr[n];
    const int d  = rowptr[n + 1] - rp;
    float acc[8] = {};
    int j = 0;
    while (j + 16 <= d) {
        int sA = srcs[rp + j + li];
        int sB = srcs[rp + j + 4 + li];
        int sC = srcs[rp + j + 8 + li];
        int sD = srcs[rp + j + 12 + li];
        uint4 u[16];
#pragma unroll
        for (int t = 0; t < 4; ++t) u[t]      = hlq[(long)__shfl(sA, gbase + t) * 4 + li];
#pragma unroll
        for (int t = 0; t < 4; ++t) u[4 + t]  = hlq[(long)__shfl(sB, gbase + t) * 4 + li];
#pragma unroll
        for (int t = 0; t < 4; ++t) u[8 + t]  = hlq[(long)__shfl(sC, gbase + t) * 4 + li];
#pragma unroll
        for (int t = 0; t < 4; ++t) u[12 + t] = hlq[(long)__shfl(sD, gbase + t) * 4 + li];
#pragma unroll
        for (int t = 0; t < 16; ++t) addup(acc, u[t]);
        j += 16;
    }
    while (j + 4 <= d) {
        int sA = srcs[rp + j + li];
        uint4 u[4];
#pragma unroll
        for (int t = 0; t < 4; ++t) u[t] = hlq[(long)__shfl(sA, gbase + t) * 4 + li];
#pragma unroll
        for (int t = 0; t < 4; ++t) addup(acc, u[t]);
        j += 4;
    }
    int r = d - j;                     // 0..3
    if (r > 0) {
        int sA = srcs[rp + j + ((li < r) ? li : 0)];
#pragma unroll
        for (int t = 0; t < 3; ++t) {
            if (t < r) {
                uint4 u = hlq[(long)__shfl(sA, gbase + t) * 4 + li];
                addup(acc, u);
            }
        }
    }
    const float dinv = (d > 0) ? (1.f / (float)d) : 1.f;
    float4 hA = *reinterpret_cast<const float4*>(&hr[(long)n * OUT_DIM + 8 * li]);
    float4 hB = *reinterpret_cast<const float4*>(&hr[(long)n * OUT_DIM + 8 * li + 4]);
    float4 vA, vB;
    vA.x = fmaf(acc[0], dinv, hA.x); vA.y = fmaf(acc[1], dinv, hA.y);
    vA.z = fmaf(acc[2], dinv, hA.z); vA.w = fmaf(acc[3], dinv, hA.w);
    vB.x = fmaf(acc[4], dinv, hB.x); vB.y = fmaf(acc[5], dinv, hB.y);
    vB.z = fmaf(acc[6], dinv, hB.z); vB.w = fmaf(acc[7], dinv, hB.w);
    vA.x = (vA.x > 0.f) ? vA.x : SLOPE * vA.x;
    vA.y = (vA.y > 0.f) ? vA.y : SLOPE * vA.y;
    vA.z = (vA.z > 0.f) ? vA.z : SLOPE * vA.z;
    vA.w = (vA.w > 0.f) ? vA.w : SLOPE * vA.w;
    vB.x = (vB.x > 0.f) ? vB.x : SLOPE * vB.x;
    vB.y = (vB.y > 0.f) ? vB.y : SLOPE * vB.y;
    vB.z = (vB.z > 0.f) ? vB.z : SLOPE * vB.z;
    vB.w = (vB.w > 0.f) ? vB.w : SLOPE * vB.w;
    *reinterpret_cast<float4*>(&z[(long)n * OUT_DIM + 8 * li]) = vA;
    *reinterpret_cast<float4*>(&z[(long)n * OUT_DIM + 8 * li + 4]) = vB;
}

extern "C" void kernel_launch(void* const* d_in, const int* in_sizes, int n_in,
                              void* d_out, int out_size, void* d_ws, size_t ws_size,
                              hipStream_t stream) {
    const float* x   = (const float*)d_in[0];
    const int*   ei  = (const int*)d_in[1];
    const float* Wl1 = (const float*)d_in[2];
    const float* Wr1 = (const float*)d_in[3];
    const float* b1  = (const float*)d_in[4];
    const float* Wl2 = (const float*)d_in[5];
    const float* Wr2 = (const float*)d_in[6];
    const float* b2  = (const float*)d_in[7];

    const int N = in_sizes[0] / IN_DIM;
    const int E = in_sizes[1] / 2;
    const int* src = ei;
    const int* dst = ei + E;
    const int NB = (N + 255) >> NPB_SHIFT;   // buckets (<= 512)

    char* p = (char*)d_ws;
    int* bhist    = (int*)p;           p += sizeof(int) * NBMAX;
    int* ebase    = (int*)p;           p += sizeof(int) * NBMAX;
    int* pbase    = (int*)p;           p += sizeof(int) * NBMAX;
    int* bcur     = (int*)p;           p += sizeof(int) * NBMAX;
    int* rowptr   = (int*)p;           p += sizeof(int) * (N + 4);
    uint32* pairs = (uint32*)p;        p += sizeof(uint32) * ((size_t)E + 16 * NBMAX);
    int* srcs     = (int*)p;           p += sizeof(int) * E;
    ushort16* xl  = (ushort16*)p;      p += sizeof(ushort16) * (size_t)N * HID;
    float* xr     = (float*)p;         p += sizeof(float) * (size_t)N * HID;
    ushort16* h   = (ushort16*)p;      p += sizeof(ushort16) * (size_t)N * HID;
    ushort16* hl  = (ushort16*)p;      p += sizeof(ushort16) * (size_t)N * OUT_DIM;
    float* hr     = (float*)p;         p += sizeof(float) * (size_t)N * OUT_DIM;

    hipMemsetAsync(bhist, 0, sizeof(int) * NBMAX, stream);

    bucket_hist_kernel<<<512, 256, 0, stream>>>(dst, bhist, E);
    bucket_scan_kernel<<<1, 512, 0, stream>>>(bhist, ebase, pbase, bcur, rowptr, NB, N, E);
    partition_kernel<<<(E + CHUNK - 1) / CHUNK, 256, 0, stream>>>(src, dst, bcur, pairs, E, NB);
    fine_bin_kernel<<<NB, 256, 0, stream>>>(pairs, bhist, ebase, pbase, rowptr, srcs, N);
    gemm1_mfma_kernel<<<(N + 63) / 64, 256, 0, stream>>>(x, Wl1, Wr1, b1, xl, xr, N);
    agg1_kernel<<<(N + 31) / 32, 256, 0, stream>>>(rowptr, srcs, (const uint4*)xl, xr,
                                                   (uint4*)h, N);
    gemm2_mfma_kernel<<<(N + 63) / 64, 256, 0, stream>>>(h, Wl2, Wr2, b2, hl, hr, N);
    agg2_final_kernel<<<(N + 63) / 64, 256, 0, stream>>>(rowptr, srcs, (const uint4*)hl, hr,
                                                         (float*)d_out, N);
}